// Round 3
// baseline (965.357 us; speedup 1.0000x reference)
//
#include <hip/hip_runtime.h>

#define NB 512
#define L  2048
#define DK 128
#define DV 128

static constexpr float INV_TEMP = 1.0f / 11.313708498984761f;

// One block per batch row b.
// Phase A: scores[l] = (q[b] . k[b,l]) * INV_TEMP  -> LDS
// Phase B: softmax over L in LDS, write attn out
// Phase C: out[b,d] = sum_l p[l] * v[b,l,d]
__global__ __launch_bounds__(512)
void mvsdpa_kernel(const float* __restrict__ q,
                   const float* __restrict__ k,
                   const float* __restrict__ v,
                   float* __restrict__ out,    // (NB, DV)
                   float* __restrict__ attn)   // (NB, L)
{
    const int b    = blockIdx.x;
    const int tid  = threadIdx.x;
    const int wave = tid >> 6;      // 0..7
    const int lane = tid & 63;
    const int half = lane >> 5;     // 0 or 1  (which l of the pair)
    const int hl   = lane & 31;     // lane within half: owns dims hl*4..hl*4+3

    __shared__ float s_scores[L];        // 8 KB: scores, then probabilities
    __shared__ float s_red[16];          // cross-wave reduction scratch
    __shared__ float s_acc[8 * DV];      // 4 KB: per-wave output partials

    // q fragment for this lane's 4 dims (same for both halves)
    const float4 qf = *reinterpret_cast<const float4*>(&q[(size_t)b * DK + hl * 4]);

    // ---------------- Phase A: scores ----------------
    const float* kb = k + (size_t)b * L * DK;
    #pragma unroll 4
    for (int l0 = wave * 2; l0 < L; l0 += 16) {
        const int l = l0 + half;
        const float4 kf = *reinterpret_cast<const float4*>(&kb[(size_t)l * DK + hl * 4]);
        float d = kf.x * qf.x + kf.y * qf.y + kf.z * qf.z + kf.w * qf.w;
        // reduce across the 32 lanes of this half (masks < 32 keep halves separate)
        d += __shfl_xor(d, 1);
        d += __shfl_xor(d, 2);
        d += __shfl_xor(d, 4);
        d += __shfl_xor(d, 8);
        d += __shfl_xor(d, 16);
        if (hl == 0) s_scores[l] = d * INV_TEMP;
    }
    __syncthreads();

    // ---------------- Phase B: softmax ----------------
    // each thread owns 4 score slots: tid, tid+512, tid+1024, tid+1536
    float vals[4];
    float m = -INFINITY;
    #pragma unroll
    for (int i = 0; i < 4; ++i) {
        vals[i] = s_scores[tid + i * 512];
        m = fmaxf(m, vals[i]);
    }
    #pragma unroll
    for (int off = 1; off < 64; off <<= 1) m = fmaxf(m, __shfl_xor(m, off));
    if (lane == 0) s_red[wave] = m;
    __syncthreads();
    float bm = s_red[0];
    #pragma unroll
    for (int w = 1; w < 8; ++w) bm = fmaxf(bm, s_red[w]);

    float ls = 0.0f;
    #pragma unroll
    for (int i = 0; i < 4; ++i) {
        vals[i] = __expf(vals[i] - bm);
        ls += vals[i];
    }
    #pragma unroll
    for (int off = 1; off < 64; off <<= 1) ls += __shfl_xor(ls, off);
    if (lane == 0) s_red[8 + wave] = ls;
    __syncthreads();
    float bs = 0.0f;
    #pragma unroll
    for (int w = 0; w < 8; ++w) bs += s_red[8 + w];
    const float inv = 1.0f / bs;

    float* attn_b = attn + (size_t)b * L;
    #pragma unroll
    for (int i = 0; i < 4; ++i) {
        const float p = vals[i] * inv;
        s_scores[tid + i * 512] = p;    // own slot: no race (barrier below)
        attn_b[tid + i * 512] = p;
    }
    __syncthreads();

    // ---------------- Phase C: PV ----------------
    const float* vb = v + (size_t)b * L * DV;
    float4 acc = make_float4(0.f, 0.f, 0.f, 0.f);
    #pragma unroll 4
    for (int l0 = wave * 2; l0 < L; l0 += 16) {
        const int l = l0 + half;
        const float4 vf = *reinterpret_cast<const float4*>(&vb[(size_t)l * DV + hl * 4]);
        const float p = s_scores[l];    // broadcast within each half
        acc.x += p * vf.x;
        acc.y += p * vf.y;
        acc.z += p * vf.z;
        acc.w += p * vf.w;
    }
    // combine the two halves (lane i and i+32 hold the same dims)
    acc.x += __shfl_xor(acc.x, 32);
    acc.y += __shfl_xor(acc.y, 32);
    acc.z += __shfl_xor(acc.z, 32);
    acc.w += __shfl_xor(acc.w, 32);
    if (half == 0) {
        *reinterpret_cast<float4*>(&s_acc[wave * DV + hl * 4]) = acc;
    }
    __syncthreads();
    if (tid < DV) {
        float o = 0.0f;
        #pragma unroll
        for (int w = 0; w < 8; ++w) o += s_acc[w * DV + tid];
        out[(size_t)b * DV + tid] = o;
    }
}

extern "C" void kernel_launch(void* const* d_in, const int* in_sizes, int n_in,
                              void* d_out, int out_size, void* d_ws, size_t ws_size,
                              hipStream_t stream) {
    const float* q = (const float*)d_in[0];
    const float* k = (const float*)d_in[1];
    const float* v = (const float*)d_in[2];
    float* out  = (float*)d_out;            // first NB*DV floats
    float* attn = out + (size_t)NB * DV;    // then NB*L floats
    mvsdpa_kernel<<<NB, 512, 0, stream>>>(q, k, v, out, attn);
}